// Round 1
// baseline (297.233 us; speedup 1.0000x reference)
//
#include <hip/hip_runtime.h>
#include <hip/hip_bf16.h>

#define N_SEQ 4096
#define DIM   128
#define NH    4
#define DH    32
#define BATCH 4

// scale = (1/sqrt(32)) * log2(e): softmax computed in exp2 domain
#define QSCALE 0.25503495870989204f

typedef __bf16 bf16x8 __attribute__((ext_vector_type(8)));
typedef float  f32x4  __attribute__((ext_vector_type(4)));

#define MFMA(a, b, c) __builtin_amdgcn_mfma_f32_16x16x32_bf16((a), (b), (c), 0, 0, 0)

static __device__ __forceinline__ bf16x8 cvt8(const float* __restrict__ p) {
    const float4* f4 = reinterpret_cast<const float4*>(p);
    float4 a = f4[0], b = f4[1];
    bf16x8 r;
    r[0] = (__bf16)a.x; r[1] = (__bf16)a.y; r[2] = (__bf16)a.z; r[3] = (__bf16)a.w;
    r[4] = (__bf16)b.x; r[5] = (__bf16)b.y; r[6] = (__bf16)b.z; r[7] = (__bf16)b.w;
    return r;
}

// ---------------------------------------------------------------------------
// Kernel 1: fused QKV projection.  out = x @ W^T + b  (torch Linear)
// grid = (N/64, B, 3) ; block = 256 (4 waves, each wave: 16 rows x 128 cols)
// Q -> Qs[bh][n][dh] bf16, pre-scaled by QSCALE
// K -> Kb[bh][n][dh] bf16
// V -> Vt[bh][dh][n] bf16   (transposed for PV B-fragments)
// ---------------------------------------------------------------------------
__global__ __launch_bounds__(256) void proj_qkv(
    const float* __restrict__ xq, const float* __restrict__ xk, const float* __restrict__ xv,
    const float* __restrict__ Wq, const float* __restrict__ bq,
    const float* __restrict__ Wk, const float* __restrict__ bk,
    const float* __restrict__ Wv, const float* __restrict__ bv,
    __bf16* __restrict__ Qs, __bf16* __restrict__ Kb, __bf16* __restrict__ Vt)
{
    const int z = blockIdx.z;
    const float* x    = (z == 0) ? xq : ((z == 1) ? xk : xv);
    const float* W    = (z == 0) ? Wq : ((z == 1) ? Wk : Wv);
    const float* bias = (z == 0) ? bq : ((z == 1) ? bk : bv);
    const int b    = blockIdx.y;
    const int wave = threadIdx.x >> 6;
    const int lane = threadIdx.x & 63;
    const int quad = lane >> 4, l15 = lane & 15;
    const int n0   = blockIdx.x * 64 + wave * 16;

    // A-fragments: 16 input rows, full K=128 split into 4 chunks of 32
    bf16x8 a[4];
    const float* xrow = x + (b * N_SEQ + n0 + l15) * DIM + quad * 8;
    a[0] = cvt8(xrow);      a[1] = cvt8(xrow + 32);
    a[2] = cvt8(xrow + 64); a[3] = cvt8(xrow + 96);

    for (int t = 0; t < 8; t++) {           // 8 output-col tiles of 16
        f32x4 acc = {0.f, 0.f, 0.f, 0.f};
        const float* wrow = W + (t * 16 + l15) * DIM + quad * 8;  // B[k=c][n=d]=W[d][c]
        acc = MFMA(a[0], cvt8(wrow),      acc);
        acc = MFMA(a[1], cvt8(wrow + 32), acc);
        acc = MFMA(a[2], cvt8(wrow + 64), acc);
        acc = MFMA(a[3], cvt8(wrow + 96), acc);

        const int d  = t * 16 + l15;        // D-frag: col = lane&15
        const int h  = d >> 5, dh = d & 31;
        const float bias_v = bias[d];
        if (z == 0) {
            __bf16* dst = Qs + ((b * NH + h) * N_SEQ) * DH + dh;
            #pragma unroll
            for (int r = 0; r < 4; r++) {   // D-frag: row = quad*4+r
                const int n = n0 + quad * 4 + r;
                dst[n * DH] = (__bf16)((acc[r] + bias_v) * QSCALE);
            }
        } else if (z == 1) {
            __bf16* dst = Kb + ((b * NH + h) * N_SEQ) * DH + dh;
            #pragma unroll
            for (int r = 0; r < 4; r++) {
                const int n = n0 + quad * 4 + r;
                dst[n * DH] = (__bf16)(acc[r] + bias_v);
            }
        } else {
            __bf16* dst = Vt + ((b * NH + h) * DH + dh) * N_SEQ;
            #pragma unroll
            for (int r = 0; r < 4; r++) {
                const int n = n0 + quad * 4 + r;
                dst[n] = (__bf16)(acc[r] + bias_v);
            }
        }
    }
}

// ---------------------------------------------------------------------------
// Kernel 2: flash attention.  grid = 1024 (bh = bid&15 for XCD/L2 locality),
// block = 256; each wave owns a 16-query tile, loops 32-key blocks.
// S-tile: D[m=q=quad*4+r][n=key=lane&15];  P round-trips LDS into A-layout.
// ---------------------------------------------------------------------------
__global__ __launch_bounds__(256) void flash_attn(
    const __bf16* __restrict__ Qs, const __bf16* __restrict__ Kb,
    const __bf16* __restrict__ Vt, __bf16* __restrict__ ctxb)
{
    __shared__ __bf16 Plds[4][16][40];       // per-wave private; stride 40 kills conflicts
    const int bid  = blockIdx.x;
    const int bh   = bid & 15;               // consecutive blocks cycle bh -> XCD locality
    const int qt   = bid >> 4;
    const int wave = threadIdx.x >> 6, lane = threadIdx.x & 63;
    const int quad = lane >> 4, l15 = lane & 15;
    const int n0   = qt * 64 + wave * 16;

    const __bf16* Qp = Qs + (bh * N_SEQ) * DH;
    const __bf16* Kp = Kb + (bh * N_SEQ) * DH;
    const __bf16* Vp = Vt + (bh * DH) * N_SEQ;

    // Q A-fragment: row m = lane&15, k = quad*8+j  (Dh=32 = one MFMA K)
    bf16x8 qf = *(const bf16x8*)(Qp + (n0 + l15) * DH + quad * 8);

    f32x4 ctx0 = {0.f, 0.f, 0.f, 0.f}, ctx1 = {0.f, 0.f, 0.f, 0.f};
    float m[4] = {-1e30f, -1e30f, -1e30f, -1e30f};
    float l[4] = {0.f, 0.f, 0.f, 0.f};

    for (int k0 = 0; k0 < N_SEQ; k0 += 32) {
        // B-frag for S=Q*K^T: B[k=c][n=key] = K[key][c] -> contiguous K rows
        bf16x8 kf0 = *(const bf16x8*)(Kp + (k0 + l15) * DH + quad * 8);
        bf16x8 kf1 = *(const bf16x8*)(Kp + (k0 + 16 + l15) * DH + quad * 8);
        f32x4 z4 = {0.f, 0.f, 0.f, 0.f};
        f32x4 s0 = MFMA(qf, kf0, z4);        // keys k0..k0+15,  col=l15
        f32x4 s1 = MFMA(qf, kf1, z4);        // keys k0+16..+31, col=l15

        #pragma unroll
        for (int r = 0; r < 4; r++) {        // row q = quad*4 + r
            float t = fmaxf(s0[r], s1[r]);
            t = fmaxf(t, __shfl_xor(t, 1));
            t = fmaxf(t, __shfl_xor(t, 2));
            t = fmaxf(t, __shfl_xor(t, 4));
            t = fmaxf(t, __shfl_xor(t, 8)); // row-max over 16 lanes (stays in quad)
            const float mn = fmaxf(m[r], t);
            const float al = __builtin_amdgcn_exp2f(m[r] - mn);
            const float p0 = __builtin_amdgcn_exp2f(s0[r] - mn);
            const float p1 = __builtin_amdgcn_exp2f(s1[r] - mn);
            m[r] = mn;
            l[r] = l[r] * al + (p0 + p1);    // per-lane partial row sum (reduced at end)
            ctx0[r] *= al;  ctx1[r] *= al;
            Plds[wave][quad * 4 + r][l15]      = (__bf16)p0;
            Plds[wave][quad * 4 + r][16 + l15] = (__bf16)p1;
        }
        // P in A-layout: A[m=l15][k=quad*8+j] (same-wave DS ops are ordered; no barrier)
        bf16x8 pf  = *(const bf16x8*)(&Plds[wave][l15][quad * 8]);
        // B-frag for PV: B[k=key][n=d] = V[key][d] = Vt[d][key] -> contiguous Vt rows
        bf16x8 vf0 = *(const bf16x8*)(Vp + l15 * N_SEQ + k0 + quad * 8);
        bf16x8 vf1 = *(const bf16x8*)(Vp + (16 + l15) * N_SEQ + k0 + quad * 8);
        ctx0 = MFMA(pf, vf0, ctx0);          // d = 0..15
        ctx1 = MFMA(pf, vf1, ctx1);          // d = 16..31
    }

    const int b = bh >> 2, h = bh & 3;
    #pragma unroll
    for (int r = 0; r < 4; r++) {
        float ls = l[r];
        ls += __shfl_xor(ls, 1); ls += __shfl_xor(ls, 2);
        ls += __shfl_xor(ls, 4); ls += __shfl_xor(ls, 8);
        const float inv = 1.0f / ls;
        const int n = n0 + quad * 4 + r;
        __bf16* dst = ctxb + (b * N_SEQ + n) * DIM + h * DH;
        dst[l15]      = (__bf16)(ctx0[r] * inv);
        dst[16 + l15] = (__bf16)(ctx1[r] * inv);
    }
}

// ---------------------------------------------------------------------------
// Kernel 3: output projection.  out = ctx @ Wo^T + bo (fp32 out)
// grid = (N/64, B), block = 256
// ---------------------------------------------------------------------------
__global__ __launch_bounds__(256) void out_proj(
    const __bf16* __restrict__ ctxb, const float* __restrict__ Wo,
    const float* __restrict__ bo, float* __restrict__ out)
{
    const int b    = blockIdx.y;
    const int wave = threadIdx.x >> 6, lane = threadIdx.x & 63;
    const int quad = lane >> 4, l15 = lane & 15;
    const int n0   = blockIdx.x * 64 + wave * 16;

    bf16x8 a[4];
    const __bf16* crow = ctxb + (b * N_SEQ + n0 + l15) * DIM + quad * 8;
    a[0] = *(const bf16x8*)(crow);
    a[1] = *(const bf16x8*)(crow + 32);
    a[2] = *(const bf16x8*)(crow + 64);
    a[3] = *(const bf16x8*)(crow + 96);

    for (int t = 0; t < 8; t++) {
        f32x4 acc = {0.f, 0.f, 0.f, 0.f};
        const float* wrow = Wo + (t * 16 + l15) * DIM + quad * 8;
        acc = MFMA(a[0], cvt8(wrow),      acc);
        acc = MFMA(a[1], cvt8(wrow + 32), acc);
        acc = MFMA(a[2], cvt8(wrow + 64), acc);
        acc = MFMA(a[3], cvt8(wrow + 96), acc);

        const int d = t * 16 + l15;
        const float bias_v = bo[d];
        #pragma unroll
        for (int r = 0; r < 4; r++) {
            const int n = n0 + quad * 4 + r;
            out[(b * N_SEQ + n) * DIM + d] = acc[r] + bias_v;
        }
    }
}

// ---------------------------------------------------------------------------
extern "C" void kernel_launch(void* const* d_in, const int* in_sizes, int n_in,
                              void* d_out, int out_size, void* d_ws, size_t ws_size,
                              hipStream_t stream)
{
    const float* query = (const float*)d_in[0];
    const float* key   = (const float*)d_in[1];
    const float* value = (const float*)d_in[2];
    const float* Wq = (const float*)d_in[3];
    const float* bq = (const float*)d_in[4];
    const float* Wk = (const float*)d_in[5];
    const float* bk = (const float*)d_in[6];
    const float* Wv = (const float*)d_in[7];
    const float* bv = (const float*)d_in[8];
    const float* Wo = (const float*)d_in[9];
    const float* bo = (const float*)d_in[10];
    float* out = (float*)d_out;

    char* ws = (char*)d_ws;
    const size_t e = (size_t)BATCH * N_SEQ * DIM;   // 2,097,152 elements
    __bf16* Qs   = (__bf16*)(ws);                   // 4 MB  [B,H,N,32] scaled
    __bf16* Kb   = (__bf16*)(ws + 2 * e);           // 4 MB  [B,H,N,32]
    __bf16* Vt   = (__bf16*)(ws + 4 * e);           // 4 MB  [B,H,32,N]
    __bf16* ctxb = (__bf16*)(ws + 6 * e);           // 4 MB  [B,N,128]

    proj_qkv<<<dim3(64, BATCH, 3), 256, 0, stream>>>(
        query, key, value, Wq, bq, Wk, bk, Wv, bv, Qs, Kb, Vt);
    flash_attn<<<dim3(1024), 256, 0, stream>>>(Qs, Kb, Vt, ctxb);
    out_proj<<<dim3(64, BATCH), 256, 0, stream>>>(ctxb, Wo, bo, out);
}